// Round 1
// baseline (25243.661 us; speedup 1.0000x reference)
//
#include <hip/hip_runtime.h>
#include <math.h>

#define TT 512
#define BB 64
#define DIN 256
#define HH 512
#define DOUT 256

#define AS 772          // padded k-stride (772 % 32 == 4, mult of 4 for float4)
#define GS 33           // gates LDS stride

#define W_FLOATS (32*AS)
#define A_FLOATS (16*AS)
#define SMEM_FLOATS (W_FLOATS + A_FLOATS + 16*GS + 32 + 128)

#define FCS 516         // fc LDS stride (516 % 32 == 4)

// ---------------- grid barrier (2-level, 8 groups x 32 blocks) ----------------
__device__ __forceinline__ void grid_arrive(unsigned* bar) {
    __threadfence();                                  // release: wb local L2
    int grp = (int)(blockIdx.x >> 5);
    if (atomicAdd(&bar[grp*16], 1u) == 31u) {         // last in group
        atomicExch(&bar[grp*16], 0u);                 // reset own count first
        if (atomicAdd(&bar[128], 1u) == 7u) {         // last group
            atomicExch(&bar[128], 0u);
            atomicAdd(&bar[160], 1u);                 // bump generation -> release
        }
    }
}

__device__ __forceinline__ void grid_wait(unsigned* bar, unsigned target) {
    while (__hip_atomic_load(&bar[160], __ATOMIC_ACQUIRE, __HIP_MEMORY_SCOPE_AGENT) < target) {
        __builtin_amdgcn_s_sleep(2);
    }
    __threadfence();                                  // acquire: inv caches
}

// ---------------- staging helpers ----------------
__device__ __forceinline__ void load_w(float* __restrict__ w_l, float* __restrict__ b_l,
                                       const float* __restrict__ Whh,
                                       const float* __restrict__ Wih,
                                       const float* __restrict__ bias,
                                       int u0, int tid) {
    // 32 rows: cc -> global gate-col C = (cc>>3)*512 + u0 + (cc&7)
    // row layout in LDS: k in [0,512) = Whh, k in [512,768) = Wih
    for (int r = 0; r < 24; ++r) {
        int id = tid + 256*r;           // 0..6143 (32 rows * 192 float4)
        int cc = id / 192;
        int j  = id % 192;
        int C  = (cc >> 3)*HH + u0 + (cc & 7);
        float4 v;
        int k;
        if (j < 128) { v = ((const float4*)(Whh + (size_t)C*HH))[j];       k = 4*j; }
        else         { v = ((const float4*)(Wih + (size_t)C*DIN))[j-128];  k = 512 + 4*(j-128); }
        *(float4*)(w_l + cc*AS + k) = v;
    }
    if (tid < 32) {
        int C = (tid >> 3)*HH + u0 + (tid & 7);
        b_l[tid] = bias[C];
    }
}

__device__ __forceinline__ void stage_x(float* __restrict__ a_l,
                                        const float* __restrict__ src, // row base for b0
                                        int tid) {
    // 16 rows x 64 float4 into a_l[b][512..768)
    for (int r = 0; r < 4; ++r) {
        int id = tid + 256*r;
        int b = id >> 6, j = id & 63;
        float4 v = ((const float4*)(src + (size_t)b*DIN))[j];
        *(float4*)(a_l + b*AS + 512 + 4*j) = v;
    }
}

__device__ __forceinline__ void stage_x_zero(float* __restrict__ a_l, int tid) {
    for (int r = 0; r < 4; ++r) {
        int id = tid + 256*r;
        int b = id >> 6, j = id & 63;
        *(float4*)(a_l + b*AS + 512 + 4*j) = make_float4(0.f,0.f,0.f,0.f);
    }
}

// ---------------- persistent LSTM kernel ----------------
__global__ __launch_bounds__(256, 1)
void lstm_persist(const float* __restrict__ x, const float* __restrict__ target,
                  const float* __restrict__ h0, const float* __restrict__ c0,
                  const float* __restrict__ eWih, const float* __restrict__ eWhh,
                  const float* __restrict__ eb,
                  const float* __restrict__ dWih, const float* __restrict__ dWhh,
                  const float* __restrict__ db,
                  float* __restrict__ hs, float* __restrict__ hbuf,
                  unsigned* __restrict__ bar)
{
    extern __shared__ float sm[];
    float* w_l = sm;                    // 32 x AS
    float* a_l = sm + W_FLOATS;         // 16 x AS  ([h | x])
    float* g_l = a_l + A_FLOATS;        // 16 x GS
    float* b_l = g_l + 16*GS;           // 32
    float* c_l = b_l + 32;              // 128  (16 b x 8 u)

    const int tid = (int)threadIdx.x;
    const int ib  = (int)(blockIdx.x & 3);     // b-tile (4 x 16 batches)
    const int ij  = (int)(blockIdx.x >> 2);    // unit-tile (64 x 8 units)
    const int b0  = ib * 16;
    const int u0  = ij * 8;

    // encoder weights + bias
    load_w(w_l, b_l, eWhh, eWih, eb, u0, tid);
    // c init from cell_state
    if (tid < 128) {
        int b = tid >> 3, u = tid & 7;
        c_l[tid] = c0[(size_t)(b0 + b)*HH + u0 + u];
    }
    // stage x for s=0 (encoder x[0])
    stage_x(a_l, x + (size_t)b0*DIN, tid);
    __syncthreads();

    const int kc = tid & 7;            // k-chunk lane (low 3 bits -> shfl_xor 1/2/4)
    const int bt = (tid >> 3) & 3;     // 4 row-groups of 4
    const int ct = tid >> 5;           // 8 col-groups of 4

    for (int s = 0; s < 1024; ++s) {
        if (tid == 0 && s > 0) grid_wait(bar, (unsigned)s);
        __syncthreads();

        if (s == 512) {                // switch to decoder weights
            load_w(w_l, b_l, dWhh, dWih, db, u0, tid);
        }
        // stage h_{t-1} into a_l[b][0..512)
        {
            const float* hsrc = (s == 0) ? (h0 + (size_t)b0*HH)
                                         : (hbuf + (size_t)((s & 1))*BB*HH + (size_t)b0*HH);
            for (int r = 0; r < 8; ++r) {
                int id = tid + 256*r;
                int b = id >> 7, j = id & 127;
                float4 v = ((const float4*)(hsrc + (size_t)b*HH))[j];
                *(float4*)(a_l + b*AS + 4*j) = v;
            }
        }
        __syncthreads();

        // ---- gates GEMM: [16 b x 32 cols] over k=768, k split 8 ways ----
        float acc[4][4] = {};
        const float* ap = a_l + (bt*4)*AS + 4*kc;
        const float* wp = w_l + (ct*4)*AS + 4*kc;
        #pragma unroll 4
        for (int i = 0; i < 24; ++i) {
            float4 av[4], wv[4];
            #pragma unroll
            for (int q = 0; q < 4; ++q) av[q] = *(const float4*)(ap + q*AS + 32*i);
            #pragma unroll
            for (int q = 0; q < 4; ++q) wv[q] = *(const float4*)(wp + q*AS + 32*i);
            #pragma unroll
            for (int bb2 = 0; bb2 < 4; ++bb2) {
                #pragma unroll
                for (int cc2 = 0; cc2 < 4; ++cc2) {
                    acc[bb2][cc2] += av[bb2].x*wv[cc2].x + av[bb2].y*wv[cc2].y
                                   + av[bb2].z*wv[cc2].z + av[bb2].w*wv[cc2].w;
                }
            }
        }
        // reduce over the 8 k-chunk lanes (kc = low 3 bits of lane id)
        #pragma unroll
        for (int bb2 = 0; bb2 < 4; ++bb2) {
            #pragma unroll
            for (int cc2 = 0; cc2 < 4; ++cc2) {
                float v = acc[bb2][cc2];
                v += __shfl_xor(v, 1, 64);
                v += __shfl_xor(v, 2, 64);
                v += __shfl_xor(v, 4, 64);
                acc[bb2][cc2] = v;
            }
        }
        if (kc == 0) {
            #pragma unroll
            for (int bb2 = 0; bb2 < 4; ++bb2) {
                #pragma unroll
                for (int cc2 = 0; cc2 < 4; ++cc2) {
                    g_l[(bt*4 + bb2)*GS + ct*4 + cc2] = acc[bb2][cc2] + b_l[ct*4 + cc2];
                }
            }
        }
        __syncthreads();

        // ---- elementwise LSTM update for owned (b, unit) ----
        if (tid < 128) {
            int b = tid >> 3, u = tid & 7;
            float gi = g_l[b*GS + u];
            float gf = g_l[b*GS + 8 + u];
            float gg = g_l[b*GS + 16 + u];
            float go = g_l[b*GS + 24 + u];
            float ii = 1.f / (1.f + expf(-gi));
            float ff = 1.f / (1.f + expf(-gf));
            float g2 = tanhf(gg);
            float oo = 1.f / (1.f + expf(-go));
            float c  = ff * c_l[tid] + ii * g2;
            c_l[tid] = c;
            float h  = oo * tanhf(c);
            int gb = b0 + b, gu = u0 + u;
            hbuf[(size_t)((s & 1) ^ 1)*BB*HH + (size_t)gb*HH + gu] = h;
            if (s >= 512) hs[((size_t)(s - 512)*BB + gb)*HH + gu] = h;
        }
        __syncthreads();
        if (tid == 0) grid_arrive(bar);

        // ---- overlap: stage next step's x during barrier wait ----
        int ns = s + 1;
        if (ns < 1024) {
            if (ns == 512) {
                stage_x_zero(a_l, tid);                         // decoder t=0 input = 0
            } else if (ns < 512) {
                stage_x(a_l, x + ((size_t)ns*BB + b0)*DIN, tid);
            } else {
                stage_x(a_l, target + ((size_t)(ns - 513)*BB + b0)*DOUT, tid);
            }
        }
    }
}

// ---------------- FC (logits) kernel ----------------
__global__ __launch_bounds__(256, 1)
void fc_kernel(const float* __restrict__ hs, const float* __restrict__ W,
               const float* __restrict__ bias, float* __restrict__ out)
{
    extern __shared__ float sm[];
    float* hs_l = sm;              // 16 x FCS
    float* w_l  = sm + 16*FCS;     // 32 x FCS

    const int tid = (int)threadIdx.x;
    const int rb = (int)(blockIdx.x >> 3);    // 2048 row-blocks of 16
    const int cb = (int)(blockIdx.x & 7);     // 8 col-blocks of 32

    for (int r = 0; r < 8; ++r) {
        int id = tid + 256*r;
        int b = id >> 7, j = id & 127;
        float4 v = ((const float4*)(hs + (size_t)(rb*16 + b)*HH))[j];
        *(float4*)(hs_l + b*FCS + 4*j) = v;
    }
    for (int r = 0; r < 16; ++r) {
        int id = tid + 256*r;
        int c = id >> 7, j = id & 127;
        float4 v = ((const float4*)(W + (size_t)(cb*32 + c)*HH))[j];
        *(float4*)(w_l + c*FCS + 4*j) = v;
    }
    __syncthreads();

    const int kc = tid & 7, bt = (tid >> 3) & 3, ct = tid >> 5;
    float acc[4][4] = {};
    const float* ap = hs_l + (bt*4)*FCS + 4*kc;
    const float* wp = w_l  + (ct*4)*FCS + 4*kc;
    #pragma unroll 4
    for (int i = 0; i < 16; ++i) {
        float4 av[4], wv[4];
        #pragma unroll
        for (int q = 0; q < 4; ++q) av[q] = *(const float4*)(ap + q*FCS + 32*i);
        #pragma unroll
        for (int q = 0; q < 4; ++q) wv[q] = *(const float4*)(wp + q*FCS + 32*i);
        #pragma unroll
        for (int bb2 = 0; bb2 < 4; ++bb2) {
            #pragma unroll
            for (int cc2 = 0; cc2 < 4; ++cc2) {
                acc[bb2][cc2] += av[bb2].x*wv[cc2].x + av[bb2].y*wv[cc2].y
                               + av[bb2].z*wv[cc2].z + av[bb2].w*wv[cc2].w;
            }
        }
    }
    #pragma unroll
    for (int bb2 = 0; bb2 < 4; ++bb2) {
        #pragma unroll
        for (int cc2 = 0; cc2 < 4; ++cc2) {
            float v = acc[bb2][cc2];
            v += __shfl_xor(v, 1, 64);
            v += __shfl_xor(v, 2, 64);
            v += __shfl_xor(v, 4, 64);
            acc[bb2][cc2] = v;
        }
    }
    if (kc == 0) {
        #pragma unroll
        for (int bb2 = 0; bb2 < 4; ++bb2) {
            #pragma unroll
            for (int cc2 = 0; cc2 < 4; ++cc2) {
                int row = rb*16 + bt*4 + bb2;
                int col = cb*32 + ct*4 + cc2;
                out[(size_t)row*DOUT + col] = acc[bb2][cc2] + bias[col];
            }
        }
    }
}

// ---------------- in-place softmax over last dim (256) ----------------
__global__ __launch_bounds__(256, 1)
void softmax_kernel(float* __restrict__ out)
{
    int row  = (int)blockIdx.x * 4 + ((int)threadIdx.x >> 6);
    int lane = (int)threadIdx.x & 63;
    float4 v = ((const float4*)(out + (size_t)row*DOUT))[lane];
    float m = fmaxf(fmaxf(v.x, v.y), fmaxf(v.z, v.w));
    #pragma unroll
    for (int d = 1; d < 64; d <<= 1) m = fmaxf(m, __shfl_xor(m, d, 64));
    float ex = expf(v.x - m), ey = expf(v.y - m), ez = expf(v.z - m), ew = expf(v.w - m);
    float ssum = ex + ey + ez + ew;
    #pragma unroll
    for (int d = 1; d < 64; d <<= 1) ssum += __shfl_xor(ssum, d, 64);
    float inv = 1.f / ssum;
    float4 o = make_float4(ex*inv, ey*inv, ez*inv, ew*inv);
    ((float4*)(out + (size_t)row*DOUT))[lane] = o;
}

// ---------------- barrier init ----------------
__global__ void init_kernel(unsigned* __restrict__ bar)
{
    bar[threadIdx.x] = 0u;   // zero 1024 uints (4 KB barrier region)
}

// ---------------- launch ----------------
extern "C" void kernel_launch(void* const* d_in, const int* in_sizes, int n_in,
                              void* d_out, int out_size, void* d_ws, size_t ws_size,
                              hipStream_t stream) {
    (void)in_sizes; (void)n_in; (void)out_size; (void)ws_size;
    const float* x      = (const float*)d_in[0];
    const float* target = (const float*)d_in[1];
    const float* h0     = (const float*)d_in[2];
    const float* c0     = (const float*)d_in[3];
    const float* eWih   = (const float*)d_in[4];
    const float* eWhh   = (const float*)d_in[5];
    const float* eb     = (const float*)d_in[6];
    const float* dWih   = (const float*)d_in[7];
    const float* dWhh   = (const float*)d_in[8];
    const float* db     = (const float*)d_in[9];
    const float* fcW    = (const float*)d_in[10];
    const float* fcb    = (const float*)d_in[11];
    float* out = (float*)d_out;

    unsigned* bar = (unsigned*)d_ws;                       // [0, 4096) bytes
    float* wsf  = (float*)d_ws;
    float* hs   = wsf + 1024;                              // decoder hidden states [T*B*H]
    float* hbuf = hs + (size_t)TT*BB*HH;                   // double-buffered h [2*B*H]

    init_kernel<<<dim3(1), dim3(1024), 0, stream>>>(bar);

    size_t lds_main = (size_t)SMEM_FLOATS * sizeof(float); // ~151 KB
    lstm_persist<<<dim3(256), dim3(256), lds_main, stream>>>(
        x, target, h0, c0, eWih, eWhh, eb, dWih, dWhh, db, hs, hbuf, bar);

    size_t lds_fc = (size_t)(48*FCS) * sizeof(float);      // ~99 KB
    fc_kernel<<<dim3(16384), dim3(256), lds_fc, stream>>>(hs, fcW, fcb, out);

    softmax_kernel<<<dim3(8192), dim3(256), 0, stream>>>(out);
}

// Round 2
// 11443.809 us; speedup vs baseline: 2.2059x; 2.2059x over previous
//
#include <hip/hip_runtime.h>
#include <math.h>

#define TT 512
#define BB 64
#define DIN 256
#define HH 512
#define DOUT 256

#define AS 772          // padded k-stride (772 % 32 == 4, mult of 4 for float4)
#define GS 33           // gates LDS stride

#define W_FLOATS (32*AS)
#define A_FLOATS (16*AS)
#define SMEM_FLOATS (W_FLOATS + A_FLOATS + 16*GS + 32 + 128)

#define FCS 516         // fc LDS stride (516 % 32 == 4)

// ---------------- staging helpers ----------------
__device__ __forceinline__ void load_w(float* __restrict__ w_l, float* __restrict__ b_l,
                                       const float* __restrict__ Whh,
                                       const float* __restrict__ Wih,
                                       const float* __restrict__ bias,
                                       int u0, int tid) {
    // 32 gate-cols: cc -> global gate-col C = (cc>>3)*512 + u0 + (cc&7)
    // row layout in LDS: k in [0,512) = Whh, k in [512,768) = Wih
    for (int r = 0; r < 24; ++r) {
        int id = tid + 256*r;           // 0..6143 (32 rows * 192 float4)
        int cc = id / 192;
        int j  = id % 192;
        int C  = (cc >> 3)*HH + u0 + (cc & 7);
        float4 v;
        int k;
        if (j < 128) { v = ((const float4*)(Whh + (size_t)C*HH))[j];       k = 4*j; }
        else         { v = ((const float4*)(Wih + (size_t)C*DIN))[j-128];  k = 512 + 4*(j-128); }
        *(float4*)(w_l + cc*AS + k) = v;
    }
    if (tid < 32) {
        int C = (tid >> 3)*HH + u0 + (tid & 7);
        b_l[tid] = bias[C];
    }
}

__device__ __forceinline__ void stage_x(float* __restrict__ a_l,
                                        const float* __restrict__ src, // row base for b0
                                        int tid) {
    // 16 rows x 64 float4 into a_l[b][512..768)
    for (int r = 0; r < 4; ++r) {
        int id = tid + 256*r;
        int b = id >> 6, j = id & 63;
        float4 v = ((const float4*)(src + (size_t)b*DIN))[j];
        *(float4*)(a_l + b*AS + 512 + 4*j) = v;
    }
}

__device__ __forceinline__ void stage_x_zero(float* __restrict__ a_l, int tid) {
    for (int r = 0; r < 4; ++r) {
        int id = tid + 256*r;
        int b = id >> 6, j = id & 63;
        *(float4*)(a_l + b*AS + 512 + 4*j) = make_float4(0.f,0.f,0.f,0.f);
    }
}

// ---------------- persistent LSTM kernel ----------------
__global__ __launch_bounds__(256, 1)
void lstm_persist(const float* __restrict__ x, const float* __restrict__ target,
                  const float* __restrict__ h0, const float* __restrict__ c0,
                  const float* __restrict__ eWih, const float* __restrict__ eWhh,
                  const float* __restrict__ eb,
                  const float* __restrict__ dWih, const float* __restrict__ dWhh,
                  const float* __restrict__ db,
                  float* __restrict__ hs, float* __restrict__ hbuf,
                  unsigned* __restrict__ bar)
{
    extern __shared__ float sm[];
    float* w_l = sm;                    // 32 x AS
    float* a_l = sm + W_FLOATS;         // 16 x AS  ([h | x])
    float* g_l = a_l + A_FLOATS;        // 16 x GS
    float* b_l = g_l + 16*GS;           // 32
    float* c_l = b_l + 32;              // 128  (16 b x 8 u)

    const int tid = (int)threadIdx.x;
    // XCD-aware mapping (heuristic: xcd = blockIdx%8). Each batch-group (ib)
    // lives on one XCD pair -> barrier + h traffic stays local-ish.
    const int xcd = (int)(blockIdx.x & 7);
    const int ib  = xcd >> 1;                  // batch group 0..3 (independent!)
    const int sub = xcd & 1;                   // sub-barrier within group
    const int ij  = (int)(blockIdx.x >> 3) | (sub << 5);   // unit tile 0..63
    const int b0  = ib * 16;
    const int u0  = ij * 8;
    unsigned* gbar = bar + ib*256;             // [sub*32]=cnt, [64]=root, [96]=gen

    // encoder weights + bias
    load_w(w_l, b_l, eWhh, eWih, eb, u0, tid);
    if (tid < 128) {
        int b = tid >> 3, u = tid & 7;
        c_l[tid] = c0[(size_t)(b0 + b)*HH + u0 + u];
    }
    stage_x(a_l, x + (size_t)b0*DIN, tid);     // x for s=0
    __syncthreads();

    const int kc = tid & 7;            // k-chunk lane (low 3 bits -> shfl_xor 1/2/4)
    const int bt = (tid >> 3) & 3;     // 4 row-groups of 4
    const int ct = tid >> 5;           // 8 col-groups of 4

    for (int s = 0; s < 1024; ++s) {
        // ---- phase A: x-part GEMM (k = 512..768), no h dependence ----
        float acc[4][4] = {};
        {
            const float* ap = a_l + (bt*4)*AS + 512 + 4*kc;
            const float* wp = w_l + (ct*4)*AS + 512 + 4*kc;
            #pragma unroll
            for (int i = 0; i < 8; ++i) {
                float4 av[4], wv[4];
                #pragma unroll
                for (int q = 0; q < 4; ++q) av[q] = *(const float4*)(ap + q*AS + 32*i);
                #pragma unroll
                for (int q = 0; q < 4; ++q) wv[q] = *(const float4*)(wp + q*AS + 32*i);
                #pragma unroll
                for (int b2 = 0; b2 < 4; ++b2)
                    #pragma unroll
                    for (int c2 = 0; c2 < 4; ++c2)
                        acc[b2][c2] += av[b2].x*wv[c2].x + av[b2].y*wv[c2].y
                                     + av[b2].z*wv[c2].z + av[b2].w*wv[c2].w;
            }
        }

        // ---- wait for h_{s-1} (relaxed poll, no cache maintenance) ----
        if (tid == 0 && s > 0) {
            while (__hip_atomic_load(&gbar[96], __ATOMIC_RELAXED,
                                     __HIP_MEMORY_SCOPE_AGENT) < (unsigned)s)
                __builtin_amdgcn_s_sleep(1);
        }
        __syncthreads();

        // ---- stage h_{s-1} into a_l[b][0..512) ----
        if (s == 0) {
            const float* hsrc = h0 + (size_t)b0*HH;
            for (int r = 0; r < 8; ++r) {
                int id = tid + 256*r;
                int b = id >> 7, j = id & 127;
                float4 v = ((const float4*)(hsrc + (size_t)b*HH))[j];
                *(float4*)(a_l + b*AS + 4*j) = v;
            }
        } else {
            // agent-scope relaxed 8B loads: bypass L1/L2, read coherence point
            unsigned long long* hsrc =
                (unsigned long long*)(hbuf + (size_t)(s & 1)*BB*HH + (size_t)b0*HH);
            for (int r = 0; r < 16; ++r) {
                int id = tid + 256*r;           // 16 rows x 256 ull
                int b = id >> 8, j = id & 255;
                unsigned long long v = __hip_atomic_load(&hsrc[b*256 + j],
                        __ATOMIC_RELAXED, __HIP_MEMORY_SCOPE_AGENT);
                *(unsigned long long*)(a_l + b*AS + 2*j) = v;
            }
        }
        __syncthreads();

        // ---- phase B: h-part GEMM (k = 0..512) ----
        {
            const float* ap = a_l + (bt*4)*AS + 4*kc;
            const float* wp = w_l + (ct*4)*AS + 4*kc;
            #pragma unroll 4
            for (int i = 0; i < 16; ++i) {
                float4 av[4], wv[4];
                #pragma unroll
                for (int q = 0; q < 4; ++q) av[q] = *(const float4*)(ap + q*AS + 32*i);
                #pragma unroll
                for (int q = 0; q < 4; ++q) wv[q] = *(const float4*)(wp + q*AS + 32*i);
                #pragma unroll
                for (int b2 = 0; b2 < 4; ++b2)
                    #pragma unroll
                    for (int c2 = 0; c2 < 4; ++c2)
                        acc[b2][c2] += av[b2].x*wv[c2].x + av[b2].y*wv[c2].y
                                     + av[b2].z*wv[c2].z + av[b2].w*wv[c2].w;
            }
        }
        // reduce over the 8 k-chunk lanes
        #pragma unroll
        for (int b2 = 0; b2 < 4; ++b2)
            #pragma unroll
            for (int c2 = 0; c2 < 4; ++c2) {
                float v = acc[b2][c2];
                v += __shfl_xor(v, 1, 64);
                v += __shfl_xor(v, 2, 64);
                v += __shfl_xor(v, 4, 64);
                acc[b2][c2] = v;
            }
        if (kc == 0) {
            #pragma unroll
            for (int b2 = 0; b2 < 4; ++b2)
                #pragma unroll
                for (int c2 = 0; c2 < 4; ++c2)
                    g_l[(bt*4 + b2)*GS + ct*4 + c2] = acc[b2][c2] + b_l[ct*4 + c2];
        }
        __syncthreads();

        // ---- elementwise LSTM update for owned (b, unit) ----
        if (tid < 128) {
            int b = tid >> 3, u = tid & 7;
            float gi = g_l[b*GS + u];
            float gf = g_l[b*GS + 8 + u];
            float gg = g_l[b*GS + 16 + u];
            float go = g_l[b*GS + 24 + u];
            float ii = 1.f / (1.f + expf(-gi));
            float ff = 1.f / (1.f + expf(-gf));
            float g2 = tanhf(gg);
            float oo = 1.f / (1.f + expf(-go));
            float c  = ff * c_l[tid] + ii * g2;
            c_l[tid] = c;
            float h  = oo * tanhf(c);
            int gb = b0 + b, gu = u0 + u;
            // agent-scope relaxed store: write-through to coherence point
            __hip_atomic_store(&hbuf[(size_t)((s & 1) ^ 1)*BB*HH + (size_t)gb*HH + gu],
                               h, __ATOMIC_RELAXED, __HIP_MEMORY_SCOPE_AGENT);
            if (s >= 512) hs[((size_t)(s - 512)*BB + gb)*HH + gu] = h;
        }
        __syncthreads();   // drains vmcnt(0): all h stores globally visible

        // ---- arrive (monotonic counters, no resets, all relaxed) ----
        if (tid == 0) {
            unsigned old = __hip_atomic_fetch_add(&gbar[sub*32], 1u,
                    __ATOMIC_RELAXED, __HIP_MEMORY_SCOPE_AGENT);
            if (old == 32u*(unsigned)s + 31u) {           // last of my 32-block sub
                unsigned r = __hip_atomic_fetch_add(&gbar[64], 1u,
                        __ATOMIC_RELAXED, __HIP_MEMORY_SCOPE_AGENT);
                if (r == 2u*(unsigned)s + 1u)             // both subs done
                    __hip_atomic_fetch_add(&gbar[96], 1u,
                            __ATOMIC_RELAXED, __HIP_MEMORY_SCOPE_AGENT);
            }
        }

        // ---- block-local tail: decoder W swap + next x (overlaps barrier) ----
        if (s == 511) load_w(w_l, b_l, dWhh, dWih, db, u0, tid);
        int ns = s + 1;
        if (ns < 1024) {
            if (ns == 512)       stage_x_zero(a_l, tid);
            else if (ns < 512)   stage_x(a_l, x + ((size_t)ns*BB + b0)*DIN, tid);
            else                 stage_x(a_l, target + ((size_t)(ns - 513)*BB + b0)*DOUT, tid);
        }
        __syncthreads();   // staged x + (new W) visible before next phase A
    }
}

// ---------------- FC (logits) kernel ----------------
__global__ __launch_bounds__(256, 1)
void fc_kernel(const float* __restrict__ hs, const float* __restrict__ W,
               const float* __restrict__ bias, float* __restrict__ out)
{
    extern __shared__ float sm[];
    float* hs_l = sm;              // 16 x FCS
    float* w_l  = sm + 16*FCS;     // 32 x FCS

    const int tid = (int)threadIdx.x;
    const int rb = (int)(blockIdx.x >> 3);    // 2048 row-blocks of 16
    const int cb = (int)(blockIdx.x & 7);     // 8 col-blocks of 32

    for (int r = 0; r < 8; ++r) {
        int id = tid + 256*r;
        int b = id >> 7, j = id & 127;
        float4 v = ((const float4*)(hs + (size_t)(rb*16 + b)*HH))[j];
        *(float4*)(hs_l + b*FCS + 4*j) = v;
    }
    for (int r = 0; r < 16; ++r) {
        int id = tid + 256*r;
        int c = id >> 7, j = id & 127;
        float4 v = ((const float4*)(W + (size_t)(cb*32 + c)*HH))[j];
        *(float4*)(w_l + c*FCS + 4*j) = v;
    }
    __syncthreads();

    const int kc = tid & 7, bt = (tid >> 3) & 3, ct = tid >> 5;
    float acc[4][4] = {};
    const float* ap = hs_l + (bt*4)*FCS + 4*kc;
    const float* wp = w_l  + (ct*4)*FCS + 4*kc;
    #pragma unroll 4
    for (int i = 0; i < 16; ++i) {
        float4 av[4], wv[4];
        #pragma unroll
        for (int q = 0; q < 4; ++q) av[q] = *(const float4*)(ap + q*FCS + 32*i);
        #pragma unroll
        for (int q = 0; q < 4; ++q) wv[q] = *(const float4*)(wp + q*FCS + 32*i);
        #pragma unroll
        for (int b2 = 0; b2 < 4; ++b2)
            #pragma unroll
            for (int c2 = 0; c2 < 4; ++c2)
                acc[b2][c2] += av[b2].x*wv[c2].x + av[b2].y*wv[c2].y
                             + av[b2].z*wv[c2].z + av[b2].w*wv[c2].w;
    }
    #pragma unroll
    for (int b2 = 0; b2 < 4; ++b2)
        #pragma unroll
        for (int c2 = 0; c2 < 4; ++c2) {
            float v = acc[b2][c2];
            v += __shfl_xor(v, 1, 64);
            v += __shfl_xor(v, 2, 64);
            v += __shfl_xor(v, 4, 64);
            acc[b2][c2] = v;
        }
    if (kc == 0) {
        #pragma unroll
        for (int b2 = 0; b2 < 4; ++b2)
            #pragma unroll
            for (int c2 = 0; c2 < 4; ++c2) {
                int row = rb*16 + bt*4 + b2;
                int col = cb*32 + ct*4 + c2;
                out[(size_t)row*DOUT + col] = acc[b2][c2] + bias[col];
            }
    }
}

// ---------------- in-place softmax over last dim (256) ----------------
__global__ __launch_bounds__(256, 1)
void softmax_kernel(float* __restrict__ out)
{
    int row  = (int)blockIdx.x * 4 + ((int)threadIdx.x >> 6);
    int lane = (int)threadIdx.x & 63;
    float4 v = ((const float4*)(out + (size_t)row*DOUT))[lane];
    float m = fmaxf(fmaxf(v.x, v.y), fmaxf(v.z, v.w));
    #pragma unroll
    for (int d = 1; d < 64; d <<= 1) m = fmaxf(m, __shfl_xor(m, d, 64));
    float ex = expf(v.x - m), ey = expf(v.y - m), ez = expf(v.z - m), ew = expf(v.w - m);
    float ssum = ex + ey + ez + ew;
    #pragma unroll
    for (int d = 1; d < 64; d <<= 1) ssum += __shfl_xor(ssum, d, 64);
    float inv = 1.f / ssum;
    float4 o = make_float4(ex*inv, ey*inv, ez*inv, ew*inv);
    ((float4*)(out + (size_t)row*DOUT))[lane] = o;
}

// ---------------- barrier init ----------------
__global__ void init_kernel(unsigned* __restrict__ bar)
{
    bar[threadIdx.x] = 0u;   // zero 1024 uints (4 KB barrier region)
}

// ---------------- launch ----------------
extern "C" void kernel_launch(void* const* d_in, const int* in_sizes, int n_in,
                              void* d_out, int out_size, void* d_ws, size_t ws_size,
                              hipStream_t stream) {
    (void)in_sizes; (void)n_in; (void)out_size; (void)ws_size;
    const float* x      = (const float*)d_in[0];
    const float* target = (const float*)d_in[1];
    const float* h0     = (const float*)d_in[2];
    const float* c0     = (const float*)d_in[3];
    const float* eWih   = (const float*)d_in[4];
    const float* eWhh   = (const float*)d_in[5];
    const float* eb     = (const float*)d_in[6];
    const float* dWih   = (const float*)d_in[7];
    const float* dWhh   = (const float*)d_in[8];
    const float* db     = (const float*)d_in[9];
    const float* fcW    = (const float*)d_in[10];
    const float* fcb    = (const float*)d_in[11];
    float* out = (float*)d_out;

    unsigned* bar = (unsigned*)d_ws;                       // [0, 4096) bytes
    float* wsf  = (float*)d_ws;
    float* hs   = wsf + 1024;                              // decoder hidden states [T*B*H]
    float* hbuf = hs + (size_t)TT*BB*HH;                   // double-buffered h [2*B*H]

    init_kernel<<<dim3(1), dim3(1024), 0, stream>>>(bar);

    size_t lds_main = (size_t)SMEM_FLOATS * sizeof(float); // ~151 KB
    lstm_persist<<<dim3(256), dim3(256), lds_main, stream>>>(
        x, target, h0, c0, eWih, eWhh, eb, dWih, dWhh, db, hs, hbuf, bar);

    size_t lds_fc = (size_t)(48*FCS) * sizeof(float);      // ~99 KB
    fc_kernel<<<dim3(16384), dim3(256), lds_fc, stream>>>(hs, fcW, fcb, out);

    softmax_kernel<<<dim3(8192), dim3(256), 0, stream>>>(out);
}

// Round 3
// 7946.272 us; speedup vs baseline: 3.1768x; 1.4401x over previous
//
#include <hip/hip_runtime.h>
#include <math.h>

#define TT 512
#define BB 64
#define DIN 256
#define HH 512
#define DOUT 256

#define AS 772          // padded k-stride (772 % 32 == 4, mult of 4 for float4)
#define GS 33           // gates LDS stride

#define W_FLOATS (32*AS)
#define A_FLOATS (16*AS)
#define SMEM_FLOATS (W_FLOATS + A_FLOATS + 16*GS + 32 + 128)

#define FCS 516         // fc LDS stride (516 % 32 == 4)

// ---------------- staging helpers ----------------
__device__ __forceinline__ void load_w(float* __restrict__ w_l, float* __restrict__ b_l,
                                       const float* __restrict__ Whh,
                                       const float* __restrict__ Wih,
                                       const float* __restrict__ bias,
                                       int u0, int tid) {
    // 32 gate-cols: cc -> global gate-col C = (cc>>3)*512 + u0 + (cc&7)
    // row layout in LDS: k in [0,512) = Whh, k in [512,768) = Wih
    for (int r = 0; r < 24; ++r) {
        int id = tid + 256*r;           // 0..6143 (32 rows * 192 float4)
        int cc = id / 192;
        int j  = id % 192;
        int C  = (cc >> 3)*HH + u0 + (cc & 7);
        float4 v;
        int k;
        if (j < 128) { v = ((const float4*)(Whh + (size_t)C*HH))[j];       k = 4*j; }
        else         { v = ((const float4*)(Wih + (size_t)C*DIN))[j-128];  k = 512 + 4*(j-128); }
        *(float4*)(w_l + cc*AS + k) = v;
    }
    if (tid < 32) {
        int C = (tid >> 3)*HH + u0 + (tid & 7);
        b_l[tid] = bias[C];
    }
}

__device__ __forceinline__ void stage_x(float* __restrict__ a_l,
                                        const float* __restrict__ src, // row base for b0
                                        int tid) {
    // 16 rows x 64 float4 into a_l[b][512..768)
    for (int r = 0; r < 4; ++r) {
        int id = tid + 256*r;
        int b = id >> 6, j = id & 63;
        float4 v = ((const float4*)(src + (size_t)b*DIN))[j];
        *(float4*)(a_l + b*AS + 512 + 4*j) = v;
    }
}

__device__ __forceinline__ void stage_x_zero(float* __restrict__ a_l, int tid) {
    for (int r = 0; r < 4; ++r) {
        int id = tid + 256*r;
        int b = id >> 6, j = id & 63;
        *(float4*)(a_l + b*AS + 512 + 4*j) = make_float4(0.f,0.f,0.f,0.f);
    }
}

// ---------------- persistent LSTM kernel ----------------
__global__ __launch_bounds__(256, 1)
void lstm_persist(const float* __restrict__ x, const float* __restrict__ target,
                  const float* __restrict__ h0, const float* __restrict__ c0,
                  const float* __restrict__ eWih, const float* __restrict__ eWhh,
                  const float* __restrict__ eb,
                  const float* __restrict__ dWih, const float* __restrict__ dWhh,
                  const float* __restrict__ db,
                  float* __restrict__ hs, float* __restrict__ hbuf,
                  unsigned* __restrict__ bar)
{
    extern __shared__ float sm[];
    float* w_l = sm;                    // 32 x AS
    float* a_l = sm + W_FLOATS;         // 16 x AS  ([h | x])
    float* g_l = a_l + A_FLOATS;        // 16 x GS
    float* b_l = g_l + 16*GS;           // 32
    float* c_l = b_l + 32;              // 128  (16 b x 8 u)

    const int tid = (int)threadIdx.x;
    // XCD-aware mapping: group ib (16 batches) lives on XCD pair {2ib,2ib+1}.
    const int xcd = (int)(blockIdx.x & 7);
    const int ib  = xcd >> 1;                  // batch group 0..3 (independent)
    const int sub = xcd & 1;
    const int ij  = (int)(blockIdx.x >> 3) | (sub << 5);   // producer id 0..63
    const int b0  = ib * 16;
    const int u0  = ij * 8;
    unsigned* gflags = bar + ib*64;            // 64 monotonic per-producer flags

    // encoder weights + bias
    load_w(w_l, b_l, eWhh, eWih, eb, u0, tid);
    if (tid < 128) {
        int b = tid >> 3, u = tid & 7;
        c_l[tid] = c0[(size_t)(b0 + b)*HH + u0 + u];
    }
    stage_x(a_l, x + (size_t)b0*DIN, tid);     // x for s=0
    // h_{-1} = h0 directly into LDS
    for (int r = 0; r < 8; ++r) {
        int id = tid + 256*r;
        int b = id >> 7, j = id & 127;
        float4 v = ((const float4*)(h0 + (size_t)(b0 + b)*HH))[j];
        *(float4*)(a_l + b*AS + 4*j) = v;
    }
    __syncthreads();

    const int kc = tid & 7;            // k-chunk lane (low 3 bits -> shfl_xor 1/2/4)
    const int bt = (tid >> 3) & 3;     // 4 row-groups of 4
    const int ct = tid >> 5;           // 8 col-groups of 4

    for (int s = 0; s < 1024; ++s) {
        // ---- 1. wait for all producers of step s-1 (flag ballot, no RMW) ----
        if (s > 0) {
            if (tid < 64) {
                while (true) {
                    unsigned v = __hip_atomic_load(&gflags[tid], __ATOMIC_RELAXED,
                                                   __HIP_MEMORY_SCOPE_AGENT);
                    if (__ballot(v >= (unsigned)s) == ~0ull) break;
                    __builtin_amdgcn_s_sleep(1);
                }
            }
            __syncthreads();
        }

        // ---- 2. issue h_{s-1} loads into registers (latency hidden by phase A) ----
        unsigned long long hv[16];
        if (s > 0) {
            const unsigned long long* hsrc =
                (const unsigned long long*)(hbuf + (size_t)(s & 1)*BB*HH + (size_t)b0*HH);
            #pragma unroll
            for (int r = 0; r < 16; ++r) {
                hv[r] = __hip_atomic_load(&hsrc[r*256 + tid],
                        __ATOMIC_RELAXED, __HIP_MEMORY_SCOPE_AGENT);
            }
        }

        // ---- 3. phase A: x-part GEMM (k = 512..768), overlaps h-load flight ----
        float acc[4][4] = {};
        {
            const float* ap = a_l + (bt*4)*AS + 512 + 4*kc;
            const float* wp = w_l + (ct*4)*AS + 512 + 4*kc;
            #pragma unroll
            for (int i = 0; i < 8; ++i) {
                float4 av[4], wv[4];
                #pragma unroll
                for (int q = 0; q < 4; ++q) av[q] = *(const float4*)(ap + q*AS + 32*i);
                #pragma unroll
                for (int q = 0; q < 4; ++q) wv[q] = *(const float4*)(wp + q*AS + 32*i);
                #pragma unroll
                for (int b2 = 0; b2 < 4; ++b2)
                    #pragma unroll
                    for (int c2 = 0; c2 < 4; ++c2)
                        acc[b2][c2] += av[b2].x*wv[c2].x + av[b2].y*wv[c2].y
                                     + av[b2].z*wv[c2].z + av[b2].w*wv[c2].w;
            }
        }

        // ---- 4. spill h regs to LDS a_l[b][0..512) ----
        if (s > 0) {
            #pragma unroll
            for (int r = 0; r < 16; ++r)
                *(unsigned long long*)(a_l + r*AS + 2*tid) = hv[r];
            __syncthreads();
        }

        // ---- 5. phase B: h-part GEMM (k = 0..512) ----
        {
            const float* ap = a_l + (bt*4)*AS + 4*kc;
            const float* wp = w_l + (ct*4)*AS + 4*kc;
            #pragma unroll 4
            for (int i = 0; i < 16; ++i) {
                float4 av[4], wv[4];
                #pragma unroll
                for (int q = 0; q < 4; ++q) av[q] = *(const float4*)(ap + q*AS + 32*i);
                #pragma unroll
                for (int q = 0; q < 4; ++q) wv[q] = *(const float4*)(wp + q*AS + 32*i);
                #pragma unroll
                for (int b2 = 0; b2 < 4; ++b2)
                    #pragma unroll
                    for (int c2 = 0; c2 < 4; ++c2)
                        acc[b2][c2] += av[b2].x*wv[c2].x + av[b2].y*wv[c2].y
                                     + av[b2].z*wv[c2].z + av[b2].w*wv[c2].w;
            }
        }
        // reduce over the 8 k-chunk lanes
        #pragma unroll
        for (int b2 = 0; b2 < 4; ++b2)
            #pragma unroll
            for (int c2 = 0; c2 < 4; ++c2) {
                float v = acc[b2][c2];
                v += __shfl_xor(v, 1, 64);
                v += __shfl_xor(v, 2, 64);
                v += __shfl_xor(v, 4, 64);
                acc[b2][c2] = v;
            }
        if (kc == 0) {
            #pragma unroll
            for (int b2 = 0; b2 < 4; ++b2)
                #pragma unroll
                for (int c2 = 0; c2 < 4; ++c2)
                    g_l[(bt*4 + b2)*GS + ct*4 + c2] = acc[b2][c2] + b_l[ct*4 + c2];
        }
        __syncthreads();

        // ---- 6. elementwise LSTM update; store h to hbuf ONLY ----
        float hval = 0.f;
        if (tid < 128) {
            int b = tid >> 3, u = tid & 7;
            float gi = g_l[b*GS + u];
            float gf = g_l[b*GS + 8 + u];
            float gg = g_l[b*GS + 16 + u];
            float go = g_l[b*GS + 24 + u];
            float ii = 1.f / (1.f + expf(-gi));
            float ff = 1.f / (1.f + expf(-gf));
            float g2 = tanhf(gg);
            float oo = 1.f / (1.f + expf(-go));
            float c  = ff * c_l[tid] + ii * g2;
            c_l[tid] = c;
            hval = oo * tanhf(c);
            int gb = b0 + b, gu = u0 + u;
            __hip_atomic_store(&hbuf[(size_t)((s & 1) ^ 1)*BB*HH + (size_t)gb*HH + gu],
                               hval, __ATOMIC_RELAXED, __HIP_MEMORY_SCOPE_AGENT);
        }
        __syncthreads();   // drains vmcnt(0): the 512B h store is globally visible

        // ---- 7. publish: plain monotonic flag store (no RMW) ----
        if (tid == 0)
            __hip_atomic_store(&gflags[ij], (unsigned)(s + 1),
                               __ATOMIC_RELAXED, __HIP_MEMORY_SCOPE_AGENT);

        // ---- 8. off-critical-path tail: hs output, next x, decoder W swap ----
        if (s >= 512 && tid < 128) {
            int b = tid >> 3, u = tid & 7;
            hs[((size_t)(s - 512)*BB + (b0 + b))*HH + (u0 + u)] = hval;
        }
        if (s == 511) load_w(w_l, b_l, dWhh, dWih, db, u0, tid);
        int ns = s + 1;
        if (ns < 1024) {
            if (ns == 512)       stage_x_zero(a_l, tid);
            else if (ns < 512)   stage_x(a_l, x + ((size_t)ns*BB + b0)*DIN, tid);
            else                 stage_x(a_l, target + ((size_t)(ns - 513)*BB + b0)*DOUT, tid);
        }
        __syncthreads();   // staged x + (new W) visible before next phase A
    }
}

// ---------------- FC (logits) kernel ----------------
__global__ __launch_bounds__(256, 1)
void fc_kernel(const float* __restrict__ hs, const float* __restrict__ W,
               const float* __restrict__ bias, float* __restrict__ out)
{
    extern __shared__ float sm[];
    float* hs_l = sm;              // 16 x FCS
    float* w_l  = sm + 16*FCS;     // 32 x FCS

    const int tid = (int)threadIdx.x;
    const int rb = (int)(blockIdx.x >> 3);    // 2048 row-blocks of 16
    const int cb = (int)(blockIdx.x & 7);     // 8 col-blocks of 32

    for (int r = 0; r < 8; ++r) {
        int id = tid + 256*r;
        int b = id >> 7, j = id & 127;
        float4 v = ((const float4*)(hs + (size_t)(rb*16 + b)*HH))[j];
        *(float4*)(hs_l + b*FCS + 4*j) = v;
    }
    for (int r = 0; r < 16; ++r) {
        int id = tid + 256*r;
        int c = id >> 7, j = id & 127;
        float4 v = ((const float4*)(W + (size_t)(cb*32 + c)*HH))[j];
        *(float4*)(w_l + c*FCS + 4*j) = v;
    }
    __syncthreads();

    const int kc = tid & 7, bt = (tid >> 3) & 3, ct = tid >> 5;
    float acc[4][4] = {};
    const float* ap = hs_l + (bt*4)*FCS + 4*kc;
    const float* wp = w_l  + (ct*4)*FCS + 4*kc;
    #pragma unroll 4
    for (int i = 0; i < 16; ++i) {
        float4 av[4], wv[4];
        #pragma unroll
        for (int q = 0; q < 4; ++q) av[q] = *(const float4*)(ap + q*FCS + 32*i);
        #pragma unroll
        for (int q = 0; q < 4; ++q) wv[q] = *(const float4*)(wp + q*FCS + 32*i);
        #pragma unroll
        for (int b2 = 0; b2 < 4; ++b2)
            #pragma unroll
            for (int c2 = 0; c2 < 4; ++c2)
                acc[b2][c2] += av[b2].x*wv[c2].x + av[b2].y*wv[c2].y
                             + av[b2].z*wv[c2].z + av[b2].w*wv[c2].w;
    }
    #pragma unroll
    for (int b2 = 0; b2 < 4; ++b2)
        #pragma unroll
        for (int c2 = 0; c2 < 4; ++c2) {
            float v = acc[b2][c2];
            v += __shfl_xor(v, 1, 64);
            v += __shfl_xor(v, 2, 64);
            v += __shfl_xor(v, 4, 64);
            acc[b2][c2] = v;
        }
    if (kc == 0) {
        #pragma unroll
        for (int b2 = 0; b2 < 4; ++b2)
            #pragma unroll
            for (int c2 = 0; c2 < 4; ++c2) {
                int row = rb*16 + bt*4 + b2;
                int col = cb*32 + ct*4 + c2;
                out[(size_t)row*DOUT + col] = acc[b2][c2] + bias[col];
            }
    }
}

// ---------------- in-place softmax over last dim (256) ----------------
__global__ __launch_bounds__(256, 1)
void softmax_kernel(float* __restrict__ out)
{
    int row  = (int)blockIdx.x * 4 + ((int)threadIdx.x >> 6);
    int lane = (int)threadIdx.x & 63;
    float4 v = ((const float4*)(out + (size_t)row*DOUT))[lane];
    float m = fmaxf(fmaxf(v.x, v.y), fmaxf(v.z, v.w));
    #pragma unroll
    for (int d = 1; d < 64; d <<= 1) m = fmaxf(m, __shfl_xor(m, d, 64));
    float ex = expf(v.x - m), ey = expf(v.y - m), ez = expf(v.z - m), ew = expf(v.w - m);
    float ssum = ex + ey + ez + ew;
    #pragma unroll
    for (int d = 1; d < 64; d <<= 1) ssum += __shfl_xor(ssum, d, 64);
    float inv = 1.f / ssum;
    float4 o = make_float4(ex*inv, ey*inv, ez*inv, ew*inv);
    ((float4*)(out + (size_t)row*DOUT))[lane] = o;
}

// ---------------- barrier init ----------------
__global__ void init_kernel(unsigned* __restrict__ bar)
{
    bar[threadIdx.x] = 0u;   // zero 1024 uints (4 KB flag region)
}

// ---------------- launch ----------------
extern "C" void kernel_launch(void* const* d_in, const int* in_sizes, int n_in,
                              void* d_out, int out_size, void* d_ws, size_t ws_size,
                              hipStream_t stream) {
    (void)in_sizes; (void)n_in; (void)out_size; (void)ws_size;
    const float* x      = (const float*)d_in[0];
    const float* target = (const float*)d_in[1];
    const float* h0     = (const float*)d_in[2];
    const float* c0     = (const float*)d_in[3];
    const float* eWih   = (const float*)d_in[4];
    const float* eWhh   = (const float*)d_in[5];
    const float* eb     = (const float*)d_in[6];
    const float* dWih   = (const float*)d_in[7];
    const float* dWhh   = (const float*)d_in[8];
    const float* db     = (const float*)d_in[9];
    const float* fcW    = (const float*)d_in[10];
    const float* fcb    = (const float*)d_in[11];
    float* out = (float*)d_out;

    unsigned* bar = (unsigned*)d_ws;                       // [0, 4096) bytes
    float* wsf  = (float*)d_ws;
    float* hs   = wsf + 1024;                              // decoder hidden states [T*B*H]
    float* hbuf = hs + (size_t)TT*BB*HH;                   // double-buffered h [2*B*H]

    init_kernel<<<dim3(1), dim3(1024), 0, stream>>>(bar);

    size_t lds_main = (size_t)SMEM_FLOATS * sizeof(float); // ~151 KB
    lstm_persist<<<dim3(256), dim3(256), lds_main, stream>>>(
        x, target, h0, c0, eWih, eWhh, eb, dWih, dWhh, db, hs, hbuf, bar);

    size_t lds_fc = (size_t)(48*FCS) * sizeof(float);      // ~99 KB
    fc_kernel<<<dim3(16384), dim3(256), lds_fc, stream>>>(hs, fcW, fcb, out);

    softmax_kernel<<<dim3(8192), dim3(256), 0, stream>>>(out);
}